// Round 6
// baseline (17.698 us; speedup 1.0000x reference)
//
#include <hip/hip_runtime.h>

typedef float f32x4 __attribute__((ext_vector_type(4)));
typedef int   i32x4 __attribute__((ext_vector_type(4)));

// ---------------------------------------------------------------------------
// Kernel 1 (fast path): per-chunk hierarchical sep counts.
// Grid = B * nchunk blocks, 64 threads. Chunk = 1024 tokens, tile = 16.
// Lane i counts sep hits in tile i (16 tokens, 4x int4), wave-scan 64 lanes.
// Writes: tilePre[(b*nchunk+c)*64 + i] = seps in tiles [0,i) of chunk c
//         chunkTot[b*nchunk+c]         = seps in whole chunk c
// ---------------------------------------------------------------------------
__global__ __launch_bounds__(64) void tile_count_kernel(
        const int* __restrict__ tokens,
        const int* __restrict__ lengths,
        const int* __restrict__ sep_p,
        int* __restrict__ chunkTot,
        int* __restrict__ tilePre,
        int S, int nchunk) {
    const int lane = threadIdx.x;            // 0..63 = tile within chunk
    const int b    = blockIdx.x / nchunk;
    const int c    = blockIdx.x % nchunk;
    const int sep  = sep_p[0];
    const int len  = lengths[b];
    const int* trow = tokens + (size_t)b * S;
    const int s0 = c * 1024 + lane * 16;

    int cnt = 0;
    #pragma unroll
    for (int k = 0; k < 4; ++k) {
        const int si = s0 + k * 4;
        const i32x4 t4 = *reinterpret_cast<const i32x4*>(trow + si);
        cnt += (t4.x == sep && si + 0 < len) ? 1 : 0;
        cnt += (t4.y == sep && si + 1 < len) ? 1 : 0;
        cnt += (t4.z == sep && si + 2 < len) ? 1 : 0;
        cnt += (t4.w == sep && si + 3 < len) ? 1 : 0;
    }
    int inc = cnt;                            // inclusive scan over 64 lanes
    #pragma unroll
    for (int off = 1; off < 64; off <<= 1) {
        int up = __shfl_up(inc, off);
        if (lane >= off) inc += up;
    }
    tilePre[(size_t)blockIdx.x * 64 + lane] = inc - cnt;   // exclusive
    if (lane == 63) chunkTot[blockIdx.x] = inc;
}

// ---------------------------------------------------------------------------
// Kernel 2 (fast path): R4 structure, prefix phase replaced by tiny lookups.
// Each block: TP=16 consecutive positions of one row, 256 threads.
// ---------------------------------------------------------------------------
template <int TP>
__global__ __launch_bounds__(256) void fused_embed_v3(
        const f32x4* __restrict__ tok_emb,
        const f32x4* __restrict__ seg_emb,
        const int* __restrict__ tokens,
        const int* __restrict__ lengths,
        const int* __restrict__ sep_p,
        const int* __restrict__ chunkTot,
        const int* __restrict__ tilePre,
        f32x4* __restrict__ out,
        int S, int nseg, int V, int nchunk) {
    const int tid  = threadIdx.x;
    const int lane = tid & 63;
    const int wave = tid >> 6;               // 0..3
    const int tiles_per_row = S / TP;
    const int b    = blockIdx.x / tiles_per_row;
    const int tile = blockIdx.x % tiles_per_row;
    const int p0   = tile * TP;
    const int sep  = sep_p[0];
    const int len  = lengths[b];
    const int* trow = tokens + (size_t)b * S;

    __shared__ int seg_lds[TP];
    __shared__ int tok_lds[TP];

    // Base sep-count for [0, p0): chunk totals before c + intra-chunk prefix.
    const int c   = p0 >> 10;                // chunk index (1024 tokens/chunk)
    const int tin = (p0 >> 4) & 63;          // tile within chunk (TP == 16)
    if (wave == 0 && lane < TP) {
        int base = tilePre[((size_t)(b * nchunk + c)) * 64 + tin];
        for (int cc = 0; cc < c; ++cc) base += chunkTot[b * nchunk + cc];

        const int s = p0 + lane;
        const int t = trow[s];
        int inc = (t == sep && s < len) ? 1 : 0;
        #pragma unroll
        for (int off = 1; off < TP; off <<= 1) {
            int up = __shfl_up(inc, off);
            if (lane >= off) inc += up;
        }
        int sg = base + inc;
        if (sg >= nseg) sg = nseg - 1;       // JAX clamp-gather
        seg_lds[lane] = (s < len) ? sg : -1; // -1 = padded
        tok_lds[lane] = (t < 0) ? 0 : ((t >= V) ? V - 1 : t);
    }
    __syncthreads();

    // Gather + add + nontemporal store. One position per wave per iteration.
    const size_t out_base = ((size_t)b * S + p0) * 64 + lane;
    #pragma unroll
    for (int k = 0; k < TP / 4; ++k) {
        const int pi = wave + k * 4;
        const int sg = seg_lds[pi];
        f32x4 r = (f32x4)0.f;
        if (sg >= 0) {
            const int t = tok_lds[pi];
            const f32x4 a = tok_emb[((size_t)t  << 6) + lane];
            const f32x4 e = seg_emb[((size_t)sg << 6) + lane];
            r = a + e;
        }
        __builtin_nontemporal_store(r, &out[out_base + (size_t)pi * 64]);
    }
}

// ---------------------------------------------------------------------------
// Generic fallback (two-kernel path) for shapes the fast path doesn't cover.
// ---------------------------------------------------------------------------
__global__ __launch_bounds__(1024) void seg_scan_kernel(
        const int* __restrict__ tokens,
        const int* __restrict__ lengths,
        const int* __restrict__ sep_p,
        int* __restrict__ seg,
        int S) {
    const int b    = blockIdx.x;
    const int tid  = threadIdx.x;
    const int lane = tid & 63;
    const int wave = tid >> 6;
    const int sep  = sep_p[0];
    const int len  = lengths[b];
    const int* trow = tokens + (size_t)b * S;
    int* srow       = seg    + (size_t)b * S;

    __shared__ int wsum[16];
    __shared__ int carry_s;
    if (tid == 0) carry_s = 0;

    const int CHUNK = 4096;
    for (int base = 0; base < S; base += CHUNK) {
        const int s0 = base + tid * 4;
        int t0 = 0, t1 = 0, t2 = 0, t3 = 0;
        if (s0 + 3 < S) {
            const i32x4 t4 = *reinterpret_cast<const i32x4*>(trow + s0);
            t0 = t4.x; t1 = t4.y; t2 = t4.z; t3 = t4.w;
        } else {
            if (s0 + 0 < S) t0 = trow[s0 + 0];
            if (s0 + 1 < S) t1 = trow[s0 + 1];
            if (s0 + 2 < S) t2 = trow[s0 + 2];
            if (s0 + 3 < S) t3 = trow[s0 + 3];
        }
        int v0 = ((t0 == sep) && (s0 + 0 < len)) ? 1 : 0;
        int v1 = v0 + (((t1 == sep) && (s0 + 1 < len)) ? 1 : 0);
        int v2 = v1 + (((t2 == sep) && (s0 + 2 < len)) ? 1 : 0);
        int v3 = v2 + (((t3 == sep) && (s0 + 3 < len)) ? 1 : 0);
        const int cnt = v3;

        int ws = cnt;
        #pragma unroll
        for (int off = 1; off < 64; off <<= 1) {
            int up = __shfl_up(ws, off);
            if (lane >= off) ws += up;
        }
        if (lane == 63) wsum[wave] = ws;
        __syncthreads();

        int wave_excl = 0, total = 0;
        #pragma unroll
        for (int w = 0; w < 16; ++w) {
            int t = wsum[w];
            if (w < wave) wave_excl += t;
            total += t;
        }
        const int carry = carry_s;
        const int excl  = carry + wave_excl + (ws - cnt);

        if (s0 + 3 < S && s0 + 4 <= len) {
            i32x4 o; o.x = excl + v0; o.y = excl + v1; o.z = excl + v2; o.w = excl + v3;
            *reinterpret_cast<i32x4*>(srow + s0) = o;
        } else {
            if (s0 + 0 < S) srow[s0 + 0] = (s0 + 0 < len) ? excl + v0 : -1;
            if (s0 + 1 < S) srow[s0 + 1] = (s0 + 1 < len) ? excl + v1 : -1;
            if (s0 + 2 < S) srow[s0 + 2] = (s0 + 2 < len) ? excl + v2 : -1;
            if (s0 + 3 < S) srow[s0 + 3] = (s0 + 3 < len) ? excl + v3 : -1;
        }
        __syncthreads();
        if (tid == 0) carry_s = carry + total;
    }
}

__global__ __launch_bounds__(256) void gather_add_div_kernel(
        const f32x4* __restrict__ tok_emb,
        const f32x4* __restrict__ seg_emb,
        const int* __restrict__ tokens,
        const int* __restrict__ seg,
        f32x4* __restrict__ out,
        int D4, int nseg, int V, long long total) {
    const long long tid = (long long)blockIdx.x * blockDim.x + threadIdx.x;
    if (tid >= total) return;
    const int lane = (int)(tid % D4);
    const long long pos = tid / D4;

    const int sg_raw = seg[pos];
    f32x4 r = (f32x4)0.f;
    if (sg_raw >= 0) {
        int t = tokens[pos];
        t = (t < 0) ? 0 : ((t >= V) ? V - 1 : t);
        int sg = (sg_raw >= nseg) ? nseg - 1 : sg_raw;
        const f32x4 a = tok_emb[(size_t)t * D4 + lane];
        const f32x4 e = seg_emb[(size_t)sg * D4 + lane];
        r = a + e;
    }
    __builtin_nontemporal_store(r, &out[(size_t)pos * D4 + lane]);
}

extern "C" void kernel_launch(void* const* d_in, const int* in_sizes, int n_in,
                              void* d_out, int out_size, void* d_ws, size_t ws_size,
                              hipStream_t stream) {
    const float* tok_emb = (const float*)d_in[0];   // [V, D]
    const float* seg_emb = (const float*)d_in[1];   // [NSEG, D]
    const int*   tokens  = (const int*)d_in[2];     // [B, S]
    const int*   lengths = (const int*)d_in[3];     // [B]
    const int*   sep_p   = (const int*)d_in[4];     // scalar

    const int B    = in_sizes[3];
    const int BS   = in_sizes[2];
    const int S    = BS / B;
    const int D    = out_size / BS;
    const int nseg = in_sizes[1] / D;
    const int V    = in_sizes[0] / D;
    const int D4   = D / 4;

    constexpr int TP = 16;
    if (D4 == 64 && (S % 1024) == 0) {
        const int nchunk = S / 1024;
        int* chunkTot = (int*)d_ws;                         // B*nchunk ints
        int* tilePre  = chunkTot + B * nchunk;              // B*nchunk*64 ints

        tile_count_kernel<<<B * nchunk, 64, 0, stream>>>(
            tokens, lengths, sep_p, chunkTot, tilePre, S, nchunk);

        const int grid = BS / TP;
        fused_embed_v3<TP><<<grid, 256, 0, stream>>>(
            (const f32x4*)tok_emb, (const f32x4*)seg_emb,
            tokens, lengths, sep_p, chunkTot, tilePre,
            (f32x4*)d_out, S, nseg, V, nchunk);
    } else {
        int* seg_ws = (int*)d_ws;
        seg_scan_kernel<<<B, 1024, 0, stream>>>(tokens, lengths, sep_p, seg_ws, S);
        const long long total = (long long)BS * D4;
        const int block = 256;
        const int grid  = (int)((total + block - 1) / block);
        gather_add_div_kernel<<<grid, block, 0, stream>>>(
            (const f32x4*)tok_emb, (const f32x4*)seg_emb,
            tokens, seg_ws, (f32x4*)d_out, D4, nseg, V, total);
    }
}

// Round 7
// 12.596 us; speedup vs baseline: 1.4051x; 1.4051x over previous
//
#include <hip/hip_runtime.h>

typedef float f32x4 __attribute__((ext_vector_type(4)));
typedef int   i32x4 __attribute__((ext_vector_type(4)));

// ---------------------------------------------------------------------------
// Fused single-kernel (fast path: D4 == 64, S % TP == 0, block = 256).
// R4 structure + valid-region clamping:
//   - tiles entirely past `len` short-circuit to a pure zero-store
//   - prefix sep-count loop runs over [0, min(p0, len)) instead of [0, p0)
// Each block: TP=16 consecutive positions of one row.
// ---------------------------------------------------------------------------
template <int TP>
__global__ __launch_bounds__(256) void fused_embed_v4(
        const f32x4* __restrict__ tok_emb,
        const f32x4* __restrict__ seg_emb,
        const int* __restrict__ tokens,
        const int* __restrict__ lengths,
        const int* __restrict__ sep_p,
        f32x4* __restrict__ out,
        int S, int nseg, int V) {
    const int tid  = threadIdx.x;
    const int lane = tid & 63;
    const int wave = tid >> 6;               // 0..3
    const int tiles_per_row = S / TP;
    const int b    = blockIdx.x / tiles_per_row;
    const int tile = blockIdx.x % tiles_per_row;
    const int p0   = tile * TP;
    const int len  = lengths[b];             // block-uniform

    const size_t out_base = ((size_t)b * S + p0) * 64 + lane;

    // ---- fully-padded tile: pure zero-store, no scan, no barrier ----------
    if (p0 >= len) {
        const f32x4 z = (f32x4)0.f;
        #pragma unroll
        for (int k = 0; k < TP / 4; ++k) {
            const int pi = wave + k * 4;
            __builtin_nontemporal_store(z, (f32x4*)&out[out_base + (size_t)pi * 64]);
        }
        return;
    }

    const int sep  = sep_p[0];
    const int* trow = tokens + (size_t)b * S;

    __shared__ int wsum[4];
    __shared__ int seg_lds[TP];
    __shared__ int tok_lds[TP];

    // ---- prefix sep-count over [0, min(p0, len)) --------------------------
    const int lim = p0 < len ? p0 : len;     // == p0 here (p0 < len), kept general
    int cnt = 0;
    for (int i = tid * 4; i < lim; i += 1024) {          // p0 % 4 == 0
        const i32x4 t4 = *reinterpret_cast<const i32x4*>(trow + i);
        cnt += (t4.x == sep && i + 0 < len) ? 1 : 0;
        cnt += (t4.y == sep && i + 1 < len) ? 1 : 0;
        cnt += (t4.z == sep && i + 2 < len) ? 1 : 0;
        cnt += (t4.w == sep && i + 3 < len) ? 1 : 0;
    }
    #pragma unroll
    for (int off = 32; off; off >>= 1) cnt += __shfl_xor(cnt, off);
    if (lane == 0) wsum[wave] = cnt;
    __syncthreads();                                      // B1
    const int P0 = wsum[0] + wsum[1] + wsum[2] + wsum[3];

    // ---- tile-local inclusive scan (wave 0, TP <= 64) ---------------------
    if (wave == 0 && lane < TP) {
        const int s = p0 + lane;
        const int t = trow[s];
        int inc = (t == sep && s < len) ? 1 : 0;
        #pragma unroll
        for (int off = 1; off < TP; off <<= 1) {
            int up = __shfl_up(inc, off);
            if (lane >= off) inc += up;
        }
        int sg = P0 + inc;
        if (sg >= nseg) sg = nseg - 1;                    // JAX clamp-gather
        seg_lds[lane] = (s < len) ? sg : -1;              // -1 = padded
        tok_lds[lane] = (t < 0) ? 0 : ((t >= V) ? V - 1 : t);
    }
    __syncthreads();                                      // B2

    // ---- gather + add + NT store ------------------------------------------
    #pragma unroll
    for (int k = 0; k < TP / 4; ++k) {
        const int pi = wave + k * 4;
        const int sg = seg_lds[pi];
        f32x4 r = (f32x4)0.f;
        if (sg >= 0) {
            const int t = tok_lds[pi];
            const f32x4 a = tok_emb[((size_t)t  << 6) + lane];
            const f32x4 e = seg_emb[((size_t)sg << 6) + lane];
            r = a + e;
        }
        __builtin_nontemporal_store(r, (f32x4*)&out[out_base + (size_t)pi * 64]);
    }
}

// ---------------------------------------------------------------------------
// Generic fallback (two-kernel path) for shapes the fast path doesn't cover.
// ---------------------------------------------------------------------------
__global__ __launch_bounds__(1024) void seg_scan_kernel(
        const int* __restrict__ tokens,
        const int* __restrict__ lengths,
        const int* __restrict__ sep_p,
        int* __restrict__ seg,
        int S) {
    const int b    = blockIdx.x;
    const int tid  = threadIdx.x;
    const int lane = tid & 63;
    const int wave = tid >> 6;
    const int sep  = sep_p[0];
    const int len  = lengths[b];
    const int* trow = tokens + (size_t)b * S;
    int* srow       = seg    + (size_t)b * S;

    __shared__ int wsum[16];
    __shared__ int carry_s;
    if (tid == 0) carry_s = 0;

    const int CHUNK = 4096;
    for (int base = 0; base < S; base += CHUNK) {
        const int s0 = base + tid * 4;
        int t0 = 0, t1 = 0, t2 = 0, t3 = 0;
        if (s0 + 3 < S) {
            const i32x4 t4 = *reinterpret_cast<const i32x4*>(trow + s0);
            t0 = t4.x; t1 = t4.y; t2 = t4.z; t3 = t4.w;
        } else {
            if (s0 + 0 < S) t0 = trow[s0 + 0];
            if (s0 + 1 < S) t1 = trow[s0 + 1];
            if (s0 + 2 < S) t2 = trow[s0 + 2];
            if (s0 + 3 < S) t3 = trow[s0 + 3];
        }
        int v0 = ((t0 == sep) && (s0 + 0 < len)) ? 1 : 0;
        int v1 = v0 + (((t1 == sep) && (s0 + 1 < len)) ? 1 : 0);
        int v2 = v1 + (((t2 == sep) && (s0 + 2 < len)) ? 1 : 0);
        int v3 = v2 + (((t3 == sep) && (s0 + 3 < len)) ? 1 : 0);
        const int cnt = v3;

        int ws = cnt;
        #pragma unroll
        for (int off = 1; off < 64; off <<= 1) {
            int up = __shfl_up(ws, off);
            if (lane >= off) ws += up;
        }
        if (lane == 63) wsum[wave] = ws;
        __syncthreads();

        int wave_excl = 0, total = 0;
        #pragma unroll
        for (int w = 0; w < 16; ++w) {
            int t = wsum[w];
            if (w < wave) wave_excl += t;
            total += t;
        }
        const int carry = carry_s;
        const int excl  = carry + wave_excl + (ws - cnt);

        if (s0 + 3 < S && s0 + 4 <= len) {
            i32x4 o; o.x = excl + v0; o.y = excl + v1; o.z = excl + v2; o.w = excl + v3;
            *reinterpret_cast<i32x4*>(srow + s0) = o;
        } else {
            if (s0 + 0 < S) srow[s0 + 0] = (s0 + 0 < len) ? excl + v0 : -1;
            if (s0 + 1 < S) srow[s0 + 1] = (s0 + 1 < len) ? excl + v1 : -1;
            if (s0 + 2 < S) srow[s0 + 2] = (s0 + 2 < len) ? excl + v2 : -1;
            if (s0 + 3 < S) srow[s0 + 3] = (s0 + 3 < len) ? excl + v3 : -1;
        }
        __syncthreads();
        if (tid == 0) carry_s = carry + total;
    }
}

__global__ __launch_bounds__(256) void gather_add_div_kernel(
        const f32x4* __restrict__ tok_emb,
        const f32x4* __restrict__ seg_emb,
        const int* __restrict__ tokens,
        const int* __restrict__ seg,
        f32x4* __restrict__ out,
        int D4, int nseg, int V, long long total) {
    const long long tid = (long long)blockIdx.x * blockDim.x + threadIdx.x;
    if (tid >= total) return;
    const int lane = (int)(tid % D4);
    const long long pos = tid / D4;

    const int sg_raw = seg[pos];
    f32x4 r = (f32x4)0.f;
    if (sg_raw >= 0) {
        int t = tokens[pos];
        t = (t < 0) ? 0 : ((t >= V) ? V - 1 : t);
        int sg = (sg_raw >= nseg) ? nseg - 1 : sg_raw;
        const f32x4 a = tok_emb[(size_t)t * D4 + lane];
        const f32x4 e = seg_emb[(size_t)sg * D4 + lane];
        r = a + e;
    }
    __builtin_nontemporal_store(r, (f32x4*)&out[(size_t)pos * D4 + lane]);
}

extern "C" void kernel_launch(void* const* d_in, const int* in_sizes, int n_in,
                              void* d_out, int out_size, void* d_ws, size_t ws_size,
                              hipStream_t stream) {
    const float* tok_emb = (const float*)d_in[0];   // [V, D]
    const float* seg_emb = (const float*)d_in[1];   // [NSEG, D]
    const int*   tokens  = (const int*)d_in[2];     // [B, S]
    const int*   lengths = (const int*)d_in[3];     // [B]
    const int*   sep_p   = (const int*)d_in[4];     // scalar

    const int B    = in_sizes[3];
    const int BS   = in_sizes[2];
    const int S    = BS / B;
    const int D    = out_size / BS;
    const int nseg = in_sizes[1] / D;
    const int V    = in_sizes[0] / D;
    const int D4   = D / 4;

    constexpr int TP = 16;
    if (D4 == 64 && (S % TP) == 0) {
        const int grid = BS / TP;
        fused_embed_v4<TP><<<grid, 256, 0, stream>>>(
            (const f32x4*)tok_emb, (const f32x4*)seg_emb,
            tokens, lengths, sep_p, (f32x4*)d_out, S, nseg, V);
    } else {
        int* seg_ws = (int*)d_ws;
        seg_scan_kernel<<<B, 1024, 0, stream>>>(tokens, lengths, sep_p, seg_ws, S);
        const long long total = (long long)BS * D4;
        const int block = 256;
        const int grid  = (int)((total + block - 1) / block);
        gather_add_div_kernel<<<grid, block, 0, stream>>>(
            (const f32x4*)tok_emb, (const f32x4*)seg_emb,
            tokens, seg_ws, (f32x4*)d_out, D4, nseg, V, total);
    }
}

// Round 8
// 12.447 us; speedup vs baseline: 1.4218x; 1.0119x over previous
//
#include <hip/hip_runtime.h>

typedef float f32x4 __attribute__((ext_vector_type(4)));
typedef int   i32x4 __attribute__((ext_vector_type(4)));

// ---------------------------------------------------------------------------
// Fused single-kernel (fast path: D4 == 64, S % TP == 0, block = 256).
// v4 structure, TP = 32 (single-variable change vs R7):
//   - tiles entirely past `len` short-circuit to a pure zero-store
//   - prefix sep-count loop runs over [0, min(p0, len))
// Each block: TP consecutive positions of one row.
// ---------------------------------------------------------------------------
template <int TP>
__global__ __launch_bounds__(256) void fused_embed_v5(
        const f32x4* __restrict__ tok_emb,
        const f32x4* __restrict__ seg_emb,
        const int* __restrict__ tokens,
        const int* __restrict__ lengths,
        const int* __restrict__ sep_p,
        f32x4* __restrict__ out,
        int S, int nseg, int V) {
    const int tid  = threadIdx.x;
    const int lane = tid & 63;
    const int wave = tid >> 6;               // 0..3
    const int tiles_per_row = S / TP;
    const int b    = blockIdx.x / tiles_per_row;
    const int tile = blockIdx.x % tiles_per_row;
    const int p0   = tile * TP;
    const int len  = lengths[b];             // block-uniform

    const size_t out_base = ((size_t)b * S + p0) * 64 + lane;

    // ---- fully-padded tile: pure zero-store, no scan, no barrier ----------
    if (p0 >= len) {
        const f32x4 z = (f32x4)0.f;
        #pragma unroll
        for (int k = 0; k < TP / 4; ++k) {
            const int pi = wave + k * 4;
            __builtin_nontemporal_store(z, (f32x4*)&out[out_base + (size_t)pi * 64]);
        }
        return;
    }

    const int sep  = sep_p[0];
    const int* trow = tokens + (size_t)b * S;

    __shared__ int wsum[4];
    __shared__ int seg_lds[TP];
    __shared__ int tok_lds[TP];

    // ---- prefix sep-count over [0, min(p0, len)) --------------------------
    const int lim = p0 < len ? p0 : len;
    int cnt = 0;
    for (int i = tid * 4; i < lim; i += 1024) {          // p0 % 4 == 0
        const i32x4 t4 = *reinterpret_cast<const i32x4*>(trow + i);
        cnt += (t4.x == sep && i + 0 < len) ? 1 : 0;
        cnt += (t4.y == sep && i + 1 < len) ? 1 : 0;
        cnt += (t4.z == sep && i + 2 < len) ? 1 : 0;
        cnt += (t4.w == sep && i + 3 < len) ? 1 : 0;
    }
    #pragma unroll
    for (int off = 32; off; off >>= 1) cnt += __shfl_xor(cnt, off);
    if (lane == 0) wsum[wave] = cnt;
    __syncthreads();                                      // B1
    const int P0 = wsum[0] + wsum[1] + wsum[2] + wsum[3];

    // ---- tile-local inclusive scan (wave 0, TP <= 64) ---------------------
    if (wave == 0 && lane < TP) {
        const int s = p0 + lane;
        const int t = trow[s];
        int inc = (t == sep && s < len) ? 1 : 0;
        #pragma unroll
        for (int off = 1; off < TP; off <<= 1) {
            int up = __shfl_up(inc, off);
            if (lane >= off) inc += up;
        }
        int sg = P0 + inc;
        if (sg >= nseg) sg = nseg - 1;                    // JAX clamp-gather
        seg_lds[lane] = (s < len) ? sg : -1;              // -1 = padded
        tok_lds[lane] = (t < 0) ? 0 : ((t >= V) ? V - 1 : t);
    }
    __syncthreads();                                      // B2

    // ---- gather + add + NT store ------------------------------------------
    #pragma unroll
    for (int k = 0; k < TP / 4; ++k) {
        const int pi = wave + k * 4;
        const int sg = seg_lds[pi];
        f32x4 r = (f32x4)0.f;
        if (sg >= 0) {
            const int t = tok_lds[pi];
            const f32x4 a = tok_emb[((size_t)t  << 6) + lane];
            const f32x4 e = seg_emb[((size_t)sg << 6) + lane];
            r = a + e;
        }
        __builtin_nontemporal_store(r, (f32x4*)&out[out_base + (size_t)pi * 64]);
    }
}

// ---------------------------------------------------------------------------
// Generic fallback (two-kernel path) for shapes the fast path doesn't cover.
// ---------------------------------------------------------------------------
__global__ __launch_bounds__(1024) void seg_scan_kernel(
        const int* __restrict__ tokens,
        const int* __restrict__ lengths,
        const int* __restrict__ sep_p,
        int* __restrict__ seg,
        int S) {
    const int b    = blockIdx.x;
    const int tid  = threadIdx.x;
    const int lane = tid & 63;
    const int wave = tid >> 6;
    const int sep  = sep_p[0];
    const int len  = lengths[b];
    const int* trow = tokens + (size_t)b * S;
    int* srow       = seg    + (size_t)b * S;

    __shared__ int wsum[16];
    __shared__ int carry_s;
    if (tid == 0) carry_s = 0;

    const int CHUNK = 4096;
    for (int base = 0; base < S; base += CHUNK) {
        const int s0 = base + tid * 4;
        int t0 = 0, t1 = 0, t2 = 0, t3 = 0;
        if (s0 + 3 < S) {
            const i32x4 t4 = *reinterpret_cast<const i32x4*>(trow + s0);
            t0 = t4.x; t1 = t4.y; t2 = t4.z; t3 = t4.w;
        } else {
            if (s0 + 0 < S) t0 = trow[s0 + 0];
            if (s0 + 1 < S) t1 = trow[s0 + 1];
            if (s0 + 2 < S) t2 = trow[s0 + 2];
            if (s0 + 3 < S) t3 = trow[s0 + 3];
        }
        int v0 = ((t0 == sep) && (s0 + 0 < len)) ? 1 : 0;
        int v1 = v0 + (((t1 == sep) && (s0 + 1 < len)) ? 1 : 0);
        int v2 = v1 + (((t2 == sep) && (s0 + 2 < len)) ? 1 : 0);
        int v3 = v2 + (((t3 == sep) && (s0 + 3 < len)) ? 1 : 0);
        const int cnt = v3;

        int ws = cnt;
        #pragma unroll
        for (int off = 1; off < 64; off <<= 1) {
            int up = __shfl_up(ws, off);
            if (lane >= off) ws += up;
        }
        if (lane == 63) wsum[wave] = ws;
        __syncthreads();

        int wave_excl = 0, total = 0;
        #pragma unroll
        for (int w = 0; w < 16; ++w) {
            int t = wsum[w];
            if (w < wave) wave_excl += t;
            total += t;
        }
        const int carry = carry_s;
        const int excl  = carry + wave_excl + (ws - cnt);

        if (s0 + 3 < S && s0 + 4 <= len) {
            i32x4 o; o.x = excl + v0; o.y = excl + v1; o.z = excl + v2; o.w = excl + v3;
            *reinterpret_cast<i32x4*>(srow + s0) = o;
        } else {
            if (s0 + 0 < S) srow[s0 + 0] = (s0 + 0 < len) ? excl + v0 : -1;
            if (s0 + 1 < S) srow[s0 + 1] = (s0 + 1 < len) ? excl + v1 : -1;
            if (s0 + 2 < S) srow[s0 + 2] = (s0 + 2 < len) ? excl + v2 : -1;
            if (s0 + 3 < S) srow[s0 + 3] = (s0 + 3 < len) ? excl + v3 : -1;
        }
        __syncthreads();
        if (tid == 0) carry_s = carry + total;
    }
}

__global__ __launch_bounds__(256) void gather_add_div_kernel(
        const f32x4* __restrict__ tok_emb,
        const f32x4* __restrict__ seg_emb,
        const int* __restrict__ tokens,
        const int* __restrict__ seg,
        f32x4* __restrict__ out,
        int D4, int nseg, int V, long long total) {
    const long long tid = (long long)blockIdx.x * blockDim.x + threadIdx.x;
    if (tid >= total) return;
    const int lane = (int)(tid % D4);
    const long long pos = tid / D4;

    const int sg_raw = seg[pos];
    f32x4 r = (f32x4)0.f;
    if (sg_raw >= 0) {
        int t = tokens[pos];
        t = (t < 0) ? 0 : ((t >= V) ? V - 1 : t);
        int sg = (sg_raw >= nseg) ? nseg - 1 : sg_raw;
        const f32x4 a = tok_emb[(size_t)t * D4 + lane];
        const f32x4 e = seg_emb[(size_t)sg * D4 + lane];
        r = a + e;
    }
    __builtin_nontemporal_store(r, (f32x4*)&out[(size_t)pos * D4 + lane]);
}

extern "C" void kernel_launch(void* const* d_in, const int* in_sizes, int n_in,
                              void* d_out, int out_size, void* d_ws, size_t ws_size,
                              hipStream_t stream) {
    const float* tok_emb = (const float*)d_in[0];   // [V, D]
    const float* seg_emb = (const float*)d_in[1];   // [NSEG, D]
    const int*   tokens  = (const int*)d_in[2];     // [B, S]
    const int*   lengths = (const int*)d_in[3];     // [B]
    const int*   sep_p   = (const int*)d_in[4];     // scalar

    const int B    = in_sizes[3];
    const int BS   = in_sizes[2];
    const int S    = BS / B;
    const int D    = out_size / BS;
    const int nseg = in_sizes[1] / D;
    const int V    = in_sizes[0] / D;
    const int D4   = D / 4;

    constexpr int TP = 32;
    if (D4 == 64 && (S % TP) == 0) {
        const int grid = BS / TP;
        fused_embed_v5<TP><<<grid, 256, 0, stream>>>(
            (const f32x4*)tok_emb, (const f32x4*)seg_emb,
            tokens, lengths, sep_p, (f32x4*)d_out, S, nseg, V);
    } else {
        int* seg_ws = (int*)d_ws;
        seg_scan_kernel<<<B, 1024, 0, stream>>>(tokens, lengths, sep_p, seg_ws, S);
        const long long total = (long long)BS * D4;
        const int block = 256;
        const int grid  = (int)((total + block - 1) / block);
        gather_add_div_kernel<<<grid, block, 0, stream>>>(
            (const f32x4*)tok_emb, (const f32x4*)seg_emb,
            tokens, seg_ws, (f32x4*)d_out, D4, nseg, V, total);
    }
}